// Round 1
// baseline (1015.498 us; speedup 1.0000x reference)
//
#include <hip/hip_runtime.h>
#include <math.h>

#define NTRI 69
#define NB 128
#define IN_LEN 864
#define MS_LEN 39744
#define EPSV 1e-5f
#define K3_BLOCK 320

struct Meta {
  unsigned char l1[NTRI], l2[NTRI], lo[NTRI];
  short cg_off[NTRI];          // float offset of dense CG table per triple
  int   gch[NTRI];             // global middle-channel base of triple
  int   wc0[NTRI];             // channel base within its l (pos*576)
  int   ms_off[7];             // per-l middle channel offsets, ms_off[6]=MS_LEN
  int   w_off[6];              // complex-element offset of W_l in weights
  int   mt[6];                 // MIDDLE_TAUS[l]
  int   ntl[6];                // number of triples per l
  short tl[6][14];             // triple ids per l, in TRIPLES order
};

__constant__ double c_fac[18] = {
  1.0,1.0,2.0,6.0,24.0,120.0,720.0,5040.0,40320.0,362880.0,3628800.0,
  39916800.0,479001600.0,6227020800.0,87178291200.0,1307674368000.0,
  20922789888000.0,355687428096000.0 };

__device__ double cg_coef(int j1,int m1,int j2,int m2,int j,int m){
  if (m1+m2!=m) return 0.0;
  double pref = sqrt((2.0*j+1.0)*c_fac[j+j1-j2]*c_fac[j-j1+j2]*c_fac[j1+j2-j]/c_fac[j1+j2+j+1]);
  pref *= sqrt(c_fac[j+m]*c_fac[j-m]*c_fac[j1-m1]*c_fac[j1+m1]*c_fac[j2-m2]*c_fac[j2+m2]);
  int kmin = max(0, max(-(j-j2+m1), -(j-j1-m2)));
  int kmax = min(j1+j2-j, min(j1-m1, j2+m2));
  double s = 0.0;
  for (int k=kmin;k<=kmax;++k){
    double d = c_fac[k]*c_fac[j1+j2-j-k]*c_fac[j1-m1-k]*c_fac[j2+m2-k]*c_fac[j-j2+m1+k]*c_fac[j-j1-m2+k];
    s += ((k&1)? -1.0:1.0)/d;
  }
  return pref*s;
}

// K0: dense CG tables: per triple, C[m_idx][x_idx], y implied = m_idx-x_idx+(l1+l2-l)
__global__ void k_init_cg(float* __restrict__ cg, Meta md){
  int tri = blockIdx.x;
  int l1=md.l1[tri], l2=md.l2[tri], l=md.lo[tri];
  int n1=2*l1+1, nm=2*l+1;
  int n=nm*n1;
  for (int e=threadIdx.x; e<n; e+=blockDim.x){
    int mi=e/n1, xi=e-mi*n1;
    int m=mi-l, m1=xi-l1, m2=m-m1;
    float v=0.f;
    if (m2>=-l2 && m2<=l2) v=(float)cg_coef(l1,m1,l2,m2,l,m);
    cg[md.cg_off[tri]+e]=v;
  }
}

// K1: per-channel sum of |M|^2 over a 16-batch group and all m
__global__ __launch_bounds__(256)
void k_sumsq(const float2* __restrict__ act, const float* __restrict__ cg,
             float* __restrict__ partial, Meta md){
  int c = blockIdx.x*256 + threadIdx.x;
  if (c >= MS_LEN) return;
  int bg = blockIdx.y;
  int l=0;
  #pragma unroll
  for (int i=1;i<6;++i) if (c>=md.ms_off[i]) l=i;
  int local=c-md.ms_off[l];
  int tp=local/576, ts=local-tp*576, t=ts/24, s=ts-t*24;
  int tri=md.tl[l][tp];
  int l1=md.l1[tri], l2=md.l2[tri];
  int n1=2*l1+1, n2=2*l2+1, nm=2*l+1;
  int d=l1+l2-l;
  const float* C = cg + md.cg_off[tri];
  int a1 = 24*l1*l1 + t*n1;
  int a2 = 24*l2*l2 + s*n2;
  float ss=0.f;
  for (int b=bg*16;b<bg*16+16;++b){
    const float2* ab = act + b*IN_LEN;
    float f1r[11],f1i[11],h2r[21],h2i[21];
    #pragma unroll
    for (int x=0;x<11;++x){
      if (x<n1){ float2 v=ab[a1+x]; f1r[x]=v.x; f1i[x]=v.y; }
      else { f1r[x]=0.f; f1i[x]=0.f; }
    }
    #pragma unroll
    for (int j=0;j<21;++j){
      int y=j-10+d;
      if (y>=0 && y<n2){ float2 v=ab[a2+y]; h2r[j]=v.x; h2i[j]=v.y; }
      else { h2r[j]=0.f; h2i[j]=0.f; }
    }
    #pragma unroll
    for (int m=0;m<11;++m){
      if (m<nm){
        float fr=0.f, fi=0.f;
        #pragma unroll
        for (int x=0;x<11;++x){
          if (x<n1){
            float cv=C[m*n1+x];
            float pr=f1r[x]*h2r[m-x+10]-f1i[x]*h2i[m-x+10];
            float pi=f1r[x]*h2i[m-x+10]+f1i[x]*h2r[m-x+10];
            fr += cv*pr; fi += cv*pi;
          }
        }
        ss += fr*fr + fi*fi;
      }
    }
  }
  partial[bg*MS_LEN + c] = ss;
}

// K2: fold moving_std + batch_std into a per-channel scale
__global__ __launch_bounds__(256)
void k_scale(const float* __restrict__ partial, const float* __restrict__ mstd,
             float* __restrict__ scale, Meta md){
  int c=blockIdx.x*256+threadIdx.x;
  if (c>=MS_LEN) return;
  int l=0;
  #pragma unroll
  for (int i=1;i<6;++i) if (c>=md.ms_off[i]) l=i;
  float ss=0.f;
  #pragma unroll
  for (int g=0;g<8;++g) ss += partial[g*MS_LEN+c];
  float bstd = sqrtf(ss/(128.f*(float)(2*l+1)));
  float nstd = 0.5f*(mstd[c]+bstd);
  scale[c] = 1.f/(nstd+EPSV);
}

// K3: one workgroup per (l, b). Recompute scaled middles chunk-wise into LDS,
// then each thread owns one (o,m) pair and does the complex dot against W.
__global__ __launch_bounds__(K3_BLOCK)
void k_out(const float2* __restrict__ act, const float2* __restrict__ wts,
           const float* __restrict__ cg, const float* __restrict__ scale,
           float2* __restrict__ out, Meta md){
  int l=blockIdx.x, b=blockIdx.y;
  int nm=2*l+1;
  int tid=threadIdx.x;
  __shared__ float2 fr_s[K3_BLOCK*11];
  int P=24*nm;
  int o=tid/nm, m=tid-o*nm;          // valid only when tid<P
  float aR=0.f, aI=0.f;
  const float2* ab = act + b*IN_LEN;
  int mtl=md.mt[l];
  for (int tpi=0; tpi<md.ntl[l]; ++tpi){
    int tri=md.tl[l][tpi];
    int l1=md.l1[tri], l2=md.l2[tri];
    int n1=2*l1+1, n2=2*l2+1, d=l1+l2-l;
    const float* C=cg+md.cg_off[tri];
    for (int base=0;base<576;base+=K3_BLOCK){
      int cs=min(K3_BLOCK,576-base);
      // phase A: compute scaled fragments for cs channels
      if (tid<cs){
        int ts=base+tid; int t=ts/24, s=ts-t*24;
        float sc=scale[md.gch[tri]+ts];
        int a1=24*l1*l1+t*n1, a2=24*l2*l2+s*n2;
        float f1r[11],f1i[11],h2r[21],h2i[21];
        #pragma unroll
        for (int x=0;x<11;++x){
          if (x<n1){ float2 v=ab[a1+x]; f1r[x]=v.x; f1i[x]=v.y; }
          else { f1r[x]=0.f; f1i[x]=0.f; }
        }
        #pragma unroll
        for (int j=0;j<21;++j){
          int y=j-10+d;
          if (y>=0 && y<n2){ float2 v=ab[a2+y]; h2r[j]=v.x; h2i[j]=v.y; }
          else { h2r[j]=0.f; h2i[j]=0.f; }
        }
        #pragma unroll
        for (int mm=0;mm<11;++mm){
          if (mm<nm){
            float fr=0.f, fi=0.f;
            #pragma unroll
            for (int x=0;x<11;++x){
              if (x<n1){
                float cv=C[mm*n1+x];
                float pr=f1r[x]*h2r[mm-x+10]-f1i[x]*h2i[mm-x+10];
                float pi=f1r[x]*h2i[mm-x+10]+f1i[x]*h2r[mm-x+10];
                fr += cv*pr; fi += cv*pi;
              }
            }
            fr_s[tid*11+mm]=make_float2(fr*sc, fi*sc);
          }
        }
      }
      __syncthreads();
      // phase B: accumulate W * frag into (o,m) accumulators
      if (tid<P){
        const float2* Wp = wts + md.w_off[l] + o*mtl + md.wc0[tri] + base;
        #pragma unroll 4
        for (int k=0;k<cs;++k){
          float2 wv=Wp[k];
          float2 fv=fr_s[k*11+m];
          aR += wv.x*fv.x - wv.y*fv.y;
          aI += wv.x*fv.y + wv.y*fv.x;
        }
      }
      __syncthreads();
    }
  }
  if (tid<P){
    out[b*IN_LEN + 24*l*l + o*nm + m] = make_float2(aR,aI);
  }
}

extern "C" void kernel_launch(void* const* d_in, const int* in_sizes, int n_in,
                              void* d_out, int out_size, void* d_ws, size_t ws_size,
                              hipStream_t stream) {
  const float2* act  = (const float2*)d_in[0];
  const float2* wts  = (const float2*)d_in[1];
  const float*  mstd = (const float*)d_in[2];
  float2* out = (float2*)d_out;

  // ---- build metadata on host (deterministic, every call) ----
  Meta md;
  int t1s[NTRI], t2s[NTRI], tls[NTRI], tpos[NTRI];
  int cnt[6]={0,0,0,0,0,0};
  int n=0;
  for (int l1=0;l1<=5;++l1)
    for (int l2=0;l2<=l1;++l2)
      for (int l=l1-l2; l<=min(l1+l2,5); ++l){
        t1s[n]=l1; t2s[n]=l2; tls[n]=l; tpos[n]=cnt[l]++; ++n;
      }
  md.ms_off[0]=0;
  for (int l=0;l<6;++l){ md.mt[l]=576*cnt[l]; md.ms_off[l+1]=md.ms_off[l]+md.mt[l]; }
  for (int l=0;l<6;++l){ md.w_off[l]=24*md.ms_off[l]; md.ntl[l]=0; }
  int ncg=0;
  for (int i=0;i<NTRI;++i){
    int l=tls[i];
    md.l1[i]=(unsigned char)t1s[i]; md.l2[i]=(unsigned char)t2s[i]; md.lo[i]=(unsigned char)l;
    md.tl[l][md.ntl[l]++]=(short)i;
    md.gch[i]=md.ms_off[l]+tpos[i]*576;
    md.wc0[i]=tpos[i]*576;
    md.cg_off[i]=(short)ncg;
    ncg += (2*l+1)*(2*t1s[i]+1);
  }

  // ---- workspace layout (floats) ----
  float* ws = (float*)d_ws;
  float* cg      = ws;                 // ncg floats (~8.3K)
  float* scale   = ws + ncg;           // MS_LEN
  float* partial = scale + MS_LEN;     // 8*MS_LEN
  (void)ws_size; (void)in_sizes; (void)n_in; (void)out_size;

  k_init_cg<<<NTRI, 64, 0, stream>>>(cg, md);
  dim3 g1((MS_LEN+255)/256, 8);
  k_sumsq<<<g1, 256, 0, stream>>>(act, cg, partial, md);
  k_scale<<<(MS_LEN+255)/256, 256, 0, stream>>>(partial, mstd, scale, md);
  dim3 g3(6, NB);
  k_out<<<g3, K3_BLOCK, 0, stream>>>(act, wts, cg, scale, out, md);
}

// Round 2
// 278.769 us; speedup vs baseline: 3.6428x; 3.6428x over previous
//
#include <hip/hip_runtime.h>
#include <hip/hip_bf16.h>
#include <math.h>

#define NTRI 69
#define NB 128
#define IN_LEN 864
#define MS_LEN 39744
#define W_CPLX 953856   // 24*MS_LEN
#define EPSV 1e-5f

typedef short short8 __attribute__((ext_vector_type(8)));
typedef float f32x4 __attribute__((ext_vector_type(4)));

struct Meta {
  unsigned char l1[NTRI], l2[NTRI], lo[NTRI];
  short cg_off[NTRI];          // float offset of dense CG table per triple
  int   ms_off[7];             // per-l middle channel offsets
  int   mt[6];                 // MIDDLE_TAUS[l]
  int   Kl[6];                 // 2*mt[l] (GEMM K per l)
  int   aoff[6];               // element offset of A_l in Amat (bf16)
  int   boff[6];               // element offset of B_l in Bmat (bf16)
  int   w_off[6];              // complex-element offset of W_l in weights
  int   ntl[6];
  short tl[6][14];
};

__constant__ double c_fac[18] = {
  1.0,1.0,2.0,6.0,24.0,120.0,720.0,5040.0,40320.0,362880.0,3628800.0,
  39916800.0,479001600.0,6227020800.0,87178291200.0,1307674368000.0,
  20922789888000.0,355687428096000.0 };

__device__ double cg_coef(int j1,int m1,int j2,int m2,int j,int m){
  if (m1+m2!=m) return 0.0;
  double pref = sqrt((2.0*j+1.0)*c_fac[j+j1-j2]*c_fac[j-j1+j2]*c_fac[j1+j2-j]/c_fac[j1+j2+j+1]);
  pref *= sqrt(c_fac[j+m]*c_fac[j-m]*c_fac[j1-m1]*c_fac[j1+m1]*c_fac[j2-m2]*c_fac[j2+m2]);
  int kmin = max(0, max(-(j-j2+m1), -(j-j1-m2)));
  int kmax = min(j1+j2-j, min(j1-m1, j2+m2));
  double s = 0.0;
  for (int k=kmin;k<=kmax;++k){
    double d = c_fac[k]*c_fac[j1+j2-j-k]*c_fac[j1-m1-k]*c_fac[j2+m2-k]*c_fac[j-j2+m1+k]*c_fac[j-j1-m2+k];
    s += ((k&1)? -1.0:1.0)/d;
  }
  return pref*s;
}

__global__ void k_init_cg(float* __restrict__ cg, Meta md){
  int tri = blockIdx.x;
  int l1=md.l1[tri], l2=md.l2[tri], l=md.lo[tri];
  int n1=2*l1+1, nm=2*l+1;
  int n=nm*n1;
  for (int e=threadIdx.x; e<n; e+=blockDim.x){
    int mi=e/n1, xi=e-mi*n1;
    int m=mi-l, m1=xi-l1, m2=m-m1;
    float v=0.f;
    if (m2>=-l2 && m2<=l2) v=(float)cg_coef(l1,m1,l2,m2,l,m);
    cg[md.cg_off[tri]+e]=v;
  }
}

// One thread per (channel c, batch b): compute unscaled middle fragment,
// store bf16 into B[n][k] GEMM layout, emit per-(b,c) sum of |M|^2.
__global__ __launch_bounds__(256)
void k_mid(const float2* __restrict__ act, const float* __restrict__ cg,
           __hip_bfloat16* __restrict__ Bm, float* __restrict__ partial,
           Meta md, int b0){
  int c = blockIdx.x*256 + threadIdx.x;
  if (c >= MS_LEN) return;
  int b = b0 + blockIdx.y;
  int l=0;
  #pragma unroll
  for (int i=1;i<6;++i) if (c>=md.ms_off[i]) l=i;
  int local=c-md.ms_off[l];
  int tp=local/576, ts=local-tp*576, t=ts/24, s=ts-t*24;
  int tri=md.tl[l][tp];
  int l1=md.l1[tri], l2=md.l2[tri];
  int n1=2*l1+1, n2=2*l2+1, nm=2*l+1;
  int d=l1+l2-l;
  const float* C = cg + md.cg_off[tri];
  int a1 = 24*l1*l1 + t*n1;
  int a2 = 24*l2*l2 + s*n2;
  const float2* ab = act + b*IN_LEN;
  float f1r[11],f1i[11],h2r[21],h2i[21];
  #pragma unroll
  for (int x=0;x<11;++x){
    if (x<n1){ float2 v=ab[a1+x]; f1r[x]=v.x; f1i[x]=v.y; }
    else { f1r[x]=0.f; f1i[x]=0.f; }
  }
  #pragma unroll
  for (int j=0;j<21;++j){
    int y=j-10+d;
    if (y>=0 && y<n2){ float2 v=ab[a2+y]; h2r[j]=v.x; h2i[j]=v.y; }
    else { h2r[j]=0.f; h2i[j]=0.f; }
  }
  int K = md.Kl[l], mt = md.mt[l];
  __hip_bfloat16* Bl = Bm + md.boff[l];
  int nbase = (b - b0)*nm;
  float ss=0.f;
  #pragma unroll
  for (int m=0;m<11;++m){
    if (m<nm){
      float fr=0.f, fi=0.f;
      #pragma unroll
      for (int x=0;x<11;++x){
        if (x<n1){
          float cv=C[m*n1+x];
          float pr=f1r[x]*h2r[m-x+10]-f1i[x]*h2i[m-x+10];
          float pi=f1r[x]*h2i[m-x+10]+f1i[x]*h2r[m-x+10];
          fr += cv*pr; fi += cv*pi;
        }
      }
      ss += fr*fr + fi*fi;
      size_t row = (size_t)(nbase + m)*K;
      Bl[row + local]      = __float2bfloat16(fr);
      Bl[row + mt + local] = __float2bfloat16(fi);
    }
  }
  partial[(size_t)b*MS_LEN + c] = ss;
}

__global__ __launch_bounds__(256)
void k_scale(const float* __restrict__ partial, const float* __restrict__ mstd,
             float* __restrict__ scale, Meta md){
  int c=blockIdx.x*256+threadIdx.x;
  if (c>=MS_LEN) return;
  int l=0;
  #pragma unroll
  for (int i=1;i<6;++i) if (c>=md.ms_off[i]) l=i;
  float ss=0.f;
  for (int b=0;b<NB;++b) ss += partial[(size_t)b*MS_LEN+c];
  float bstd = sqrtf(ss/(128.f*(float)(2*l+1)));
  float nstd = 0.5f*(mstd[c]+bstd);
  scale[c] = 1.f/(nstd+EPSV);
}

// Stacked-real scaled A: rows [0,24) = real-out, [24,48) = imag-out.
__global__ __launch_bounds__(256)
void k_buildA(const float2* __restrict__ wts, const float* __restrict__ scale,
              __hip_bfloat16* __restrict__ Am, Meta md){
  int i = blockIdx.x*256+threadIdx.x;
  if (i>=W_CPLX) return;
  int l=0;
  #pragma unroll
  for (int j=1;j<6;++j) if (i>=md.w_off[j]) l=j;
  int j = i - md.w_off[l];
  int mt = md.mt[l];
  int o = j/mt, c = j - o*mt;
  float2 w = wts[i];
  float s = scale[md.ms_off[l]+c];
  size_t K = (size_t)md.Kl[l];
  __hip_bfloat16* Al = Am + md.aoff[l];
  Al[o*K + c]           = __float2bfloat16(w.x*s);
  Al[o*K + mt + c]      = __float2bfloat16(-w.y*s);
  Al[(24+o)*K + c]      = __float2bfloat16(w.y*s);
  Al[(24+o)*K + mt + c] = __float2bfloat16(w.x*s);
}

// GEMM: C[48][Nl] = A[48][K] * B[K][Nl] per l. Block = 4 waves; each wave
// owns an interleaved K-slice; 3 row-tiles x 1 col-tile of 16; LDS reduce.
__global__ __launch_bounds__(256)
void k_gemm(const __hip_bfloat16* __restrict__ Am, const __hip_bfloat16* __restrict__ Bm,
            float* __restrict__ outf, Meta md, int b0, int nb){
  int l = blockIdx.y;
  int nm = 2*l+1;
  int Nl = nb*nm;
  int ntile = blockIdx.x;
  if (ntile*16 >= Nl) return;
  int K = md.Kl[l];
  int tid = threadIdx.x;
  int lane = tid & 63, w = tid >> 6;
  int r = lane & 15, kg = lane >> 4;
  const __hip_bfloat16* Al = Am + md.aoff[l];
  const __hip_bfloat16* Bl = Bm + md.boff[l];
  const __hip_bfloat16* pa0 = Al + (size_t)(r)*K      + w*32 + kg*8;
  const __hip_bfloat16* pa1 = Al + (size_t)(16+r)*K   + w*32 + kg*8;
  const __hip_bfloat16* pa2 = Al + (size_t)(32+r)*K   + w*32 + kg*8;
  const __hip_bfloat16* pb  = Bl + (size_t)(ntile*16+r)*K + w*32 + kg*8;
  f32x4 acc0={0.f,0.f,0.f,0.f}, acc1=acc0, acc2=acc0;
  int iters = K >> 7;   // 4 waves x 32 per iteration; K % 128 == 0 always
  for (int it=0; it<iters; ++it){
    short8 vb  = *(const short8*)pb;
    short8 va0 = *(const short8*)pa0;
    short8 va1 = *(const short8*)pa1;
    short8 va2 = *(const short8*)pa2;
    acc0 = __builtin_amdgcn_mfma_f32_16x16x32_bf16(va0, vb, acc0, 0,0,0);
    acc1 = __builtin_amdgcn_mfma_f32_16x16x32_bf16(va1, vb, acc1, 0,0,0);
    acc2 = __builtin_amdgcn_mfma_f32_16x16x32_bf16(va2, vb, acc2, 0,0,0);
    pa0 += 128; pa1 += 128; pa2 += 128; pb += 128;
  }
  __shared__ float red[4*48*16];
  #pragma unroll
  for (int reg=0; reg<4; ++reg){
    int row0 = kg*4 + reg;
    red[(w*48 + row0)*16 + r]      = acc0[reg];
    red[(w*48 + 16 + row0)*16 + r] = acc1[reg];
    red[(w*48 + 32 + row0)*16 + r] = acc2[reg];
  }
  __syncthreads();
  for (int e=tid; e<768; e+=256){
    float sv = red[e] + red[768+e] + red[1536+e] + red[2304+e];
    int o = e >> 4, cc = e & 15;
    int n = ntile*16 + cc;
    int b = b0 + n/nm, m = n - (n/nm)*nm;
    int oo = (o<24)? o : o-24;
    int comp = (o<24)? 0 : 1;
    outf[((size_t)b*IN_LEN + 24*l*l + oo*nm + m)*2 + comp] = sv;
  }
}

extern "C" void kernel_launch(void* const* d_in, const int* in_sizes, int n_in,
                              void* d_out, int out_size, void* d_ws, size_t ws_size,
                              hipStream_t stream) {
  const float2* act  = (const float2*)d_in[0];
  const float2* wts  = (const float2*)d_in[1];
  const float*  mstd = (const float*)d_in[2];
  float* outf = (float*)d_out;
  (void)in_sizes; (void)n_in; (void)out_size;

  // ---- metadata ----
  Meta md;
  int t1s[NTRI], t2s[NTRI], tls[NTRI];
  int cnt[6]={0,0,0,0,0,0};
  int n=0;
  for (int l1=0;l1<=5;++l1)
    for (int l2=0;l2<=l1;++l2)
      for (int l=l1-l2; l<=min(l1+l2,5); ++l){
        t1s[n]=l1; t2s[n]=l2; tls[n]=l; cnt[l]++; ++n;
      }
  md.ms_off[0]=0;
  for (int l=0;l<6;++l){ md.mt[l]=576*cnt[l]; md.Kl[l]=2*md.mt[l]; md.ms_off[l+1]=md.ms_off[l]+md.mt[l]; }
  for (int l=0;l<6;++l){ md.w_off[l]=24*md.ms_off[l]; md.ntl[l]=0; }
  int ncg=0;
  for (int i=0;i<NTRI;++i){
    int l=tls[i];
    md.l1[i]=(unsigned char)t1s[i]; md.l2[i]=(unsigned char)t2s[i]; md.lo[i]=(unsigned char)l;
    md.tl[l][md.ntl[l]++]=(short)i;
    md.cg_off[i]=(short)ncg;
    ncg += (2*l+1)*(2*t1s[i]+1);
  }
  int atot=0;
  for (int l=0;l<6;++l){ md.aoff[l]=atot; atot += 48*md.Kl[l]; }

  // ---- ws layout (bytes, 256-aligned) ----
  size_t ob = 0;
  auto alloc = [&](size_t bytes){ size_t o = ob; ob = (ob + bytes + 255) & ~255ULL; return o; };
  size_t off_cg      = alloc((size_t)ncg*4);
  size_t off_scale   = alloc((size_t)MS_LEN*4);
  size_t off_partial = alloc((size_t)NB*MS_LEN*4);
  size_t off_A       = alloc((size_t)atot*2);
  size_t off_B       = ob;

  // per-batch B footprint: sum_l (2l+1)*Kl elements
  size_t bel_per_b = 0;
  for (int l=0;l<6;++l) bel_per_b += (size_t)(2*l+1)*md.Kl[l];
  int nb = 16;
  for (int cand : {128,64,32,16}){
    if (off_B + (size_t)cand*bel_per_b*2 <= ws_size){ nb = cand; break; }
  }
  { int bo=0; for (int l=0;l<6;++l){ md.boff[l]=bo; bo += nb*(2*l+1)*md.Kl[l]; } }

  uint8_t* wsb = (uint8_t*)d_ws;
  float* cg      = (float*)(wsb+off_cg);
  float* scale   = (float*)(wsb+off_scale);
  float* partial = (float*)(wsb+off_partial);
  __hip_bfloat16* Am = (__hip_bfloat16*)(wsb+off_A);
  __hip_bfloat16* Bm = (__hip_bfloat16*)(wsb+off_B);

  k_init_cg<<<NTRI, 64, 0, stream>>>(cg, md);
  int cblk = (MS_LEN+255)/256;
  if (nb == 128){
    k_mid<<<dim3(cblk,128), 256, 0, stream>>>(act, cg, Bm, partial, md, 0);
    k_scale<<<cblk, 256, 0, stream>>>(partial, mstd, scale, md);
    k_buildA<<<(W_CPLX+255)/256, 256, 0, stream>>>(wts, scale, Am, md);
    k_gemm<<<dim3(88,6), 256, 0, stream>>>(Am, Bm, outf, md, 0, 128);
  } else {
    for (int b0=0;b0<NB;b0+=nb)
      k_mid<<<dim3(cblk,nb), 256, 0, stream>>>(act, cg, Bm, partial, md, b0);
    k_scale<<<cblk, 256, 0, stream>>>(partial, mstd, scale, md);
    k_buildA<<<(W_CPLX+255)/256, 256, 0, stream>>>(wts, scale, Am, md);
    int tiles = nb*11/16;
    for (int b0=0;b0<NB;b0+=nb){
      k_mid<<<dim3(cblk,nb), 256, 0, stream>>>(act, cg, Bm, partial, md, b0);
      k_gemm<<<dim3(tiles,6), 256, 0, stream>>>(Am, Bm, outf, md, b0, nb);
    }
  }
}